// Round 6
// baseline (216.739 us; speedup 1.0000x reference)
//
#include <hip/hip_runtime.h>
#include <hip/hip_bf16.h>
#include <stdint.h>

// Problem constants
#define B_SZ   1024
#define GF     512
#define GC     63
#define NLEAF  64
#define IN_F   512
#define OUT_F  512
#define NTOT   (OUT_F * NLEAF)   // 32768 = GEMM N

typedef float f32x4 __attribute__((ext_vector_type(4)));
typedef __bf16 bf16x8 __attribute__((ext_vector_type(8)));

union BU { __hip_bfloat162 h; unsigned int u; };

__device__ inline void pack8(const float* f, __hip_bfloat16* dst) {
  BU a, b, c, d;
  a.h = __float22bfloat162_rn(make_float2(f[0], f[1]));
  b.h = __float22bfloat162_rn(make_float2(f[2], f[3]));
  c.h = __float22bfloat162_rn(make_float2(f[4], f[5]));
  d.h = __float22bfloat162_rn(make_float2(f[6], f[7]));
  uint4 v = make_uint4(a.u, b.u, c.u, d.u);
  *(uint4*)dst = v;
}

// ---------------------------------------------------------------------------
// k_prep, 3 block families:
//  A [0,1024):    leaf probs -> pT[l][b] (transposed, fp32)
//  B [1024,1280): xb = bf16(x_leaf)  [1024][512]
//  C [1280,1792): pwb2[n=o*64+l][i] = bf16(pw[o][i][l])  (LDS-tiled transpose)
// ---------------------------------------------------------------------------
__global__ __launch_bounds__(256, 2) void k_prep(
    const float* __restrict__ xg, const float* __restrict__ gw,
    const float* __restrict__ gb, const float* __restrict__ xl,
    const float* __restrict__ pw,
    float* __restrict__ pT, __hip_bfloat16* __restrict__ xb,
    __hip_bfloat16* __restrict__ pwb2)
{
  struct FamA { float xsr[GF]; float part[256]; float gates[GC + 1]; };
  __shared__ union { FamA a; float tile[128][66]; } sm;

  const int blk = blockIdx.x;
  const int t   = threadIdx.x;

  if (blk < B_SZ) {
    // ---- family A: leaf probs ----
    const int b = blk;
    sm.a.xsr[t]       = xg[(size_t)b * GF + t];
    sm.a.xsr[t + 256] = xg[(size_t)b * GF + 256 + t];
    __syncthreads();

    const int ks = t >> 6, g = t & 63;
    float acc = 0.f;
    if (g < GC) {
      const float* gp = gw + (size_t)(ks * 128) * GC + g;
      const float* xp = &sm.a.xsr[ks * 128];
#pragma unroll 8
      for (int k = 0; k < 128; ++k) acc += xp[k] * gp[(size_t)k * GC];
    }
    sm.a.part[t] = acc;
    __syncthreads();

    if (t < GC) {
      float s = gb[t] + sm.a.part[t] + sm.a.part[64 + t] +
                sm.a.part[128 + t] + sm.a.part[192 + t];
      sm.a.gates[t] = 1.f / (1.f + expf(-s));
    }
    __syncthreads();

    if (t < NLEAF) {
      float v = 1.f;
      int idx = 0, start = 0;
#pragma unroll
      for (int d = 0; d < 6; ++d) {
        int bit = (t >> (5 - d)) & 1;
        float gg = sm.a.gates[start + idx];
        v *= bit ? (1.f - gg) : gg;
        idx = 2 * idx + bit;
        start += (1 << d);
      }
      pT[(size_t)t * B_SZ + b] = v;       // transposed: pT[l][b]
    }
  } else if (blk < B_SZ + 256) {
    // ---- family B: x -> bf16 ----
    const int tt = (blk - B_SZ) * 256 + t;     // 0..65535, 8 elems each
    const float* src = xl + (size_t)tt * 8;
    float f[8];
    *(float4*)&f[0] = *(const float4*)(src);
    *(float4*)&f[4] = *(const float4*)(src + 4);
    pack8(f, xb + (size_t)tt * 8);
  } else {
    // ---- family C: pw [o][i][l] -> pwb2 [o*64+l][i] bf16 ----
    const int o = blk - (B_SZ + 256);          // 0..511
#pragma unroll 1
    for (int ic = 0; ic < 4; ++ic) {
      // read 128 i-rows x 64 l (coalesced), store LDS tile[i][l]
      {
        const int il = t >> 1, half = t & 1;
        const float* src = pw + (size_t)o * 32768 + (size_t)(ic * 128 + il) * 64 + half * 32;
#pragma unroll
        for (int f4 = 0; f4 < 8; ++f4)
          *(float4*)&sm.tile[il][half * 32 + f4 * 4] = *(const float4*)(src + f4 * 4);
      }
      __syncthreads();
      // write: thread (q=wid, l=lane): 32 i-values of row n = o*64+l
      {
        const int l = t & 63, q = t >> 6;
        float vals[32];
#pragma unroll
        for (int j = 0; j < 32; ++j) vals[j] = sm.tile[q * 32 + j][l];
        __hip_bfloat16* dst = pwb2 + (size_t)(o * 64 + l) * 512 + ic * 128 + q * 32;
        pack8(&vals[0],  dst);
        pack8(&vals[8],  dst + 8);
        pack8(&vals[16], dst + 16);
        pack8(&vals[24], dst + 24);
      }
      __syncthreads();
    }
  }
}

// ---------------------------------------------------------------------------
// k_gemm: pure bf16 GEMM  t[b][n] = sum_i xb[b][i] * pwb2[n][i]
//   (M=1024 b, N=32768 n=o*64+l, K=512 i), BM=256, BN=128, KI=8 x BK=64.
// Epilogue (fused, in-register): out[b][o] = sum_l pT[l][b]*(t + pb[o][l]).
// Each o lives in exactly ONE n-tile -> no split-K / atomics / reduce.
// A-frags: direct global->VGPR (xb is 1MB, L2-hot). B: glds double-buffer,
// XOR-rotated 16B chunks (b128 reads at the 8-phase bank floor).
// bid = mt*256 + nt -> bid%8 = nt%8: all 4 mt-blocks of an nt on one XCD
// (4MB B-slice per XCD = L2-resident).
// ---------------------------------------------------------------------------
__global__ __launch_bounds__(512, 2) void k_gemm(
    const __hip_bfloat16* __restrict__ xb,    // [1024][512]
    const __hip_bfloat16* __restrict__ pwb2,  // [32768][512]
    const float* __restrict__ pT,             // [64][1024]
    const float* __restrict__ pb,             // [512][64]
    float* __restrict__ out)                  // [1024][512]
{
  __shared__ __align__(16) __hip_bfloat16 bs[2][128 * 64];  // 2 x 16 KB

  const int tid  = threadIdx.x;
  const int lane = tid & 63;
  const int wid  = tid >> 6;        // 0..7
  const int quad = lane >> 4;
  const int l15  = lane & 15;

  const int bid = blockIdx.x;       // 1024 = 4 mt x 256 nt
  const int nt  = bid & 255;
  const int mt  = bid >> 8;
  const int row_m0 = mt * 256;
  const int n0     = nt * 128;

  const int wm = (wid >> 1) * 64;   // 0,64,128,192
  const int wn = (wid & 1) * 64;    // wave's o within the pair
  const int o  = nt * 2 + (wid & 1);

  // glds per-thread source offsets (2 issues/tile), XOR-rotated chunks
  int boff[2];
#pragma unroll
  for (int v = 0; v < 2; ++v) {
    int n = v * 64 + (tid >> 3);    // 0..127 local row
    int c = tid & 7;
    int q = (c - n) & 7;
    boff[v] = (n0 + n) * 512 + q * 8;
  }

  f32x4 acc[4][4];
#pragma unroll
  for (int mi = 0; mi < 4; ++mi)
#pragma unroll
    for (int ni = 0; ni < 4; ++ni)
      acc[mi][ni] = (f32x4)(0.f);

  const __hip_bfloat16* abase = xb + (size_t)(row_m0 + wm + l15) * 512 + quad * 8;

#define ISSUE(T, S)                                                           \
  {                                                                           \
    _Pragma("unroll")                                                         \
    for (int v_ = 0; v_ < 2; ++v_)                                            \
      __builtin_amdgcn_global_load_lds(                                       \
          (const __attribute__((address_space(1))) void*)                     \
              (pwb2 + boff[v_] + (T) * 64),                                   \
          (__attribute__((address_space(3))) void*)                           \
              (&bs[S][v_ * 4096 + tid * 8]),                                  \
          16, 0, 0);                                                          \
  }

  ISSUE(0, 0)   // prologue

#pragma unroll 2
  for (int it = 0; it < 8; ++it) {
    __syncthreads();                 // tile(it) staged; buffers aligned
    if (it < 7) ISSUE(it + 1, (it + 1) & 1)

    const __hip_bfloat16* bsc = &bs[it & 1][0];

    bf16x8 af[4][2];
#pragma unroll
    for (int mi = 0; mi < 4; ++mi)
#pragma unroll
      for (int ks = 0; ks < 2; ++ks)
        af[mi][ks] = *(const bf16x8*)(abase + mi * 8192 + it * 64 + ks * 32);

#pragma unroll
    for (int ks = 0; ks < 2; ++ks) {
#pragma unroll
      for (int ni = 0; ni < 4; ++ni) {
        int n = wn + ni * 16 + l15;
        int slot = (ks * 4 + quad + n) & 7;
        bf16x8 bfr = *(const bf16x8*)&bsc[n * 64 + slot * 8];
#pragma unroll
        for (int mi = 0; mi < 4; ++mi)
          acc[mi][ni] = __builtin_amdgcn_mfma_f32_16x16x32_bf16(
              af[mi][ks], bfr, acc[mi][ni], 0, 0, 0);
      }
    }
  }
#undef ISSUE

  // ---- fused epilogue: out[b][o] = sum_l pT[l][b] * (t[b][o,l] + pb[o][l]) ----
  float pbf[4];
#pragma unroll
  for (int ni = 0; ni < 4; ++ni) pbf[ni] = pb[(size_t)o * 64 + ni * 16 + l15];

  f32x4 s[4];
#pragma unroll
  for (int mi = 0; mi < 4; ++mi) {
    f32x4 sum = (f32x4)(0.f);
#pragma unroll
    for (int ni = 0; ni < 4; ++ni) {
      const f32x4 pf = *(const f32x4*)(pT + (size_t)(ni * 16 + l15) * B_SZ +
                                       row_m0 + wm + mi * 16 + quad * 4);
      sum += (acc[mi][ni] + pbf[ni]) * pf;
    }
    s[mi] = sum;
  }

  // butterfly reduce over the 16 l15-lanes (l-dimension)
#pragma unroll
  for (int msk = 1; msk <= 8; msk <<= 1) {
#pragma unroll
    for (int mi = 0; mi < 4; ++mi) {
      s[mi][0] += __shfl_xor(s[mi][0], msk, 64);
      s[mi][1] += __shfl_xor(s[mi][1], msk, 64);
      s[mi][2] += __shfl_xor(s[mi][2], msk, 64);
      s[mi][3] += __shfl_xor(s[mi][3], msk, 64);
    }
  }

  if (l15 == 0) {
#pragma unroll
    for (int mi = 0; mi < 4; ++mi) {
      int r0 = row_m0 + wm + mi * 16 + quad * 4;
      out[(size_t)(r0 + 0) * OUT_F + o] = s[mi][0];
      out[(size_t)(r0 + 1) * OUT_F + o] = s[mi][1];
      out[(size_t)(r0 + 2) * OUT_F + o] = s[mi][2];
      out[(size_t)(r0 + 3) * OUT_F + o] = s[mi][3];
    }
  }
}

// ---------------------------------------------------------------------------
extern "C" void kernel_launch(void* const* d_in, const int* in_sizes, int n_in,
                              void* d_out, int out_size, void* d_ws, size_t ws_size,
                              hipStream_t stream) {
  const float* xg = (const float*)d_in[0];   // x_gating [1024][512]
  const float* xl = (const float*)d_in[1];   // x_leaf   [1024][512]
  const float* gw = (const float*)d_in[2];   // [512][63]
  const float* gb = (const float*)d_in[3];   // [63]
  const float* pw = (const float*)d_in[4];   // [512][512][64]
  const float* pb = (const float*)d_in[5];   // [512][64]
  float* out = (float*)d_out;

  // ws: pwb2 bf16 [32768][512] (33.55 MB) | xb bf16 (1 MB) | pT fp32 (256 KB)
  const size_t PWB2_BYTES = (size_t)NTOT * IN_F * 2;
  const size_t XB_BYTES   = (size_t)B_SZ * IN_F * 2;

  __hip_bfloat16* pwb2 = (__hip_bfloat16*)d_ws;
  __hip_bfloat16* xb   = (__hip_bfloat16*)((char*)d_ws + PWB2_BYTES);
  float*          pT   = (float*)((char*)d_ws + PWB2_BYTES + XB_BYTES);

  k_prep<<<dim3(B_SZ + 256 + 512), dim3(256), 0, stream>>>(
      xg, gw, gb, xl, pw, pT, xb, pwb2);
  k_gemm<<<dim3(1024), dim3(512), 0, stream>>>(xb, pwb2, pT, pb, out);
}

// Round 7
// 168.908 us; speedup vs baseline: 1.2832x; 1.2832x over previous
//
#include <hip/hip_runtime.h>
#include <hip/hip_bf16.h>
#include <stdint.h>

// Problem constants
#define B_SZ   1024
#define GF     512
#define GC     63
#define NLEAF  64
#define IN_F   512
#define OUT_F  512

typedef float f32x4 __attribute__((ext_vector_type(4)));
typedef __bf16 bf16x8 __attribute__((ext_vector_type(8)));

struct alignas(16) BV8 { __hip_bfloat162 a, b, c, d; };
union PK8 { BV8 v; bf16x8 f; };
union BU { __hip_bfloat162 h; unsigned int u; };

__device__ inline void pack8(const float* f, __hip_bfloat16* dst) {
  BU a, b, c, d;
  a.h = __float22bfloat162_rn(make_float2(f[0], f[1]));
  b.h = __float22bfloat162_rn(make_float2(f[2], f[3]));
  c.h = __float22bfloat162_rn(make_float2(f[4], f[5]));
  d.h = __float22bfloat162_rn(make_float2(f[6], f[7]));
  *(uint4*)dst = make_uint4(a.u, b.u, c.u, d.u);
}

// ---------------------------------------------------------------------------
// Kernel 1: gatings = sigmoid(x_gating @ gw + gb); leaf_probs tree product.
// (unchanged from R5 — proven)
// ---------------------------------------------------------------------------
__global__ __launch_bounds__(512, 2) void k_leafprobs(
    const float* __restrict__ xg, const float* __restrict__ gw,
    const float* __restrict__ gb, float* __restrict__ p_ws)
{
  __shared__ float xsr[GF];
  __shared__ float part[512];
  __shared__ float gates[GC + 1];
  const int b = blockIdx.x;
  const int t = threadIdx.x;

  xsr[t] = xg[(size_t)b * GF + t];
  __syncthreads();

  const int ks = t >> 6, g = t & 63;
  float acc = 0.f;
  if (g < GC) {
    const float* gp = gw + (size_t)(ks * 64) * GC + g;
    const float* xp = &xsr[ks * 64];
#pragma unroll 8
    for (int k = 0; k < 64; ++k) acc += xp[k] * gp[(size_t)k * GC];
  }
  part[t] = acc;
  __syncthreads();

  if (t < GC) {
    float s = gb[t];
#pragma unroll
    for (int r = 0; r < 8; ++r) s += part[r * 64 + t];
    gates[t] = 1.f / (1.f + expf(-s));
  }
  __syncthreads();

  if (t < NLEAF) {
    float v = 1.f;
    int idx = 0, start = 0;
#pragma unroll
    for (int d = 0; d < 6; ++d) {
      int bit = (t >> (5 - d)) & 1;
      float gg = gates[start + idx];
      v *= bit ? (1.f - gg) : gg;
      idx = 2 * idx + bit;
      start += (1 << d);
    }
    p_ws[(size_t)b * NLEAF + t] = v;
  }
}

// ---------------------------------------------------------------------------
// Kernel 2 (FUSED): reads pw fp32 DIRECTLY (no pwb materialization).
// out[b][o] (+)= sum_{i,l} (x[b,i]*p[b,l]) * pw[o][i][l]
// BM=256 (4 waves x 64m), BN=64 (one o-tile), BK=64 l per i-step, KI=32, SK=16.
// Per iter: B fp32 tile (64o x 64l = 16 KB) global->VGPR (2-deep reg prefetch)
//   -> cvt bf16 -> ds_write (padded rows) -> 1 barrier -> A-build + 32 MFMA.
// bid -> (nt=bid&7, mt=(bid>>3)&3, kc=bid>>5): all 4 mt-blocks of a (nt,kc)
// pw-slice co-XCD & co-resident -> pw HBM-read once, L2 serves mt-reuse.
// ---------------------------------------------------------------------------
#define SK 16
#define KI 32   // 512 / SK

template <bool ATOMIC>
__global__ __launch_bounds__(256, 2) void k_fused(
    const float* __restrict__ x_leaf,   // [1024][512]
    const float* __restrict__ p_ws,     // [1024][64]
    const float* __restrict__ pw,       // [512][512][64]  ([o][i][l])
    float* __restrict__ dst)            // parts [SK][1024][512] or out
{
  __shared__ __align__(16) float           xs[256][KI + 4];   // stride 36: 36.9 KB
  __shared__ __align__(16) __hip_bfloat16  bs[2][64 * 72];    // +8 pad: 18.4 KB

  const int tid  = threadIdx.x;
  const int lane = tid & 63;
  const int wid  = tid >> 6;        // 0..3
  const int quad = lane >> 4;
  const int l15  = lane & 15;

  const int bid = blockIdx.x;       // 512
  const int nt  = bid & 7;
  const int mt  = (bid >> 3) & 3;
  const int kc  = bid >> 5;         // 0..15

  const int row_m0 = mt * 256;
  const int o0     = nt * 64;
  const int i0     = kc * KI;
  const int wm     = wid * 64;

  // ---- stage x slab [256 rows][KI] : one row per thread ----
  {
    const float* src = x_leaf + (size_t)(row_m0 + tid) * IN_F + i0;
#pragma unroll
    for (int q = 0; q < KI / 4; ++q)
      *(float4*)&xs[tid][q * 4] = *(const float4*)(src + q * 4);
  }

  // ---- p fragments fp32 (reused all K): pr[mi][ks][half4] ----
  f32x4 pr[4][2][2];
#pragma unroll
  for (int mi = 0; mi < 4; ++mi) {
    int row = row_m0 + wm + mi * 16 + l15;
#pragma unroll
    for (int ks = 0; ks < 2; ++ks) {
      const f32x4* src = (const f32x4*)(p_ws + (size_t)row * NLEAF + ks * 32 + quad * 8);
      pr[mi][ks][0] = src[0];
      pr[mi][ks][1] = src[1];
    }
  }
  { // force p-wait out of the K-loop
    float sink = 0.f;
#pragma unroll
    for (int mi = 0; mi < 4; ++mi)
#pragma unroll
      for (int ks = 0; ks < 2; ++ks)
#pragma unroll
        for (int h = 0; h < 2; ++h) {
          f32x4 v = pr[mi][ks][h];
          sink += v.x + v.y + v.z + v.w;
        }
    if (sink == 1.2345678e37f) xs[0][0] = sink;   // never taken
  }

  // ---- B-load geometry: thread = (r = tid>>2 of 64 o-rows, seg = tid&3) ----
  const int br  = tid >> 2;
  const int seg = tid & 3;
  const float* bsrc0 = pw + ((size_t)(o0 + br) * IN_F + i0) * NLEAF + seg * 16;

  f32x4 acc[4][4];
#pragma unroll
  for (int mi = 0; mi < 4; ++mi)
#pragma unroll
    for (int ni = 0; ni < 4; ++ni)
      acc[mi][ni] = (f32x4)(0.f);

  float4 rb[2][4];   // 2-deep register prefetch of the fp32 B tile

#define BLOAD(T, BUF)                                                         \
  {                                                                           \
    const float4* s_ = (const float4*)(bsrc0 + (size_t)(T) * NLEAF);          \
    rb[BUF][0] = s_[0]; rb[BUF][1] = s_[1];                                   \
    rb[BUF][2] = s_[2]; rb[BUF][3] = s_[3];                                   \
  }

  BLOAD(0, 0)
  BLOAD(1, 1)

#pragma unroll 2
  for (int it = 0; it < KI; ++it) {
    const int buf = it & 1;

    // cvt fp32 tile -> bf16 into LDS (row br, l-range seg*16..+16)
    {
      float f[16];
      *(float4*)&f[0]  = rb[buf][0];
      *(float4*)&f[4]  = rb[buf][1];
      *(float4*)&f[8]  = rb[buf][2];
      *(float4*)&f[12] = rb[buf][3];
      __hip_bfloat16* d = &bs[buf][br * 72 + seg * 16];
      pack8(&f[0], d);
      pack8(&f[8], d + 8);
    }

    if (it + 2 < KI) BLOAD(it + 2, buf)   // refill just-freed regs

    __syncthreads();   // bs[buf] visible to all waves

    float xv[4];
#pragma unroll
    for (int mi = 0; mi < 4; ++mi) xv[mi] = xs[wm + mi * 16 + l15][it];

    const __hip_bfloat16* bsc = &bs[buf][0];
#pragma unroll
    for (int ks = 0; ks < 2; ++ks) {
      bf16x8 af[4];
#pragma unroll
      for (int mi = 0; mi < 4; ++mi) {
        f32x4 lo = pr[mi][ks][0] * xv[mi];
        f32x4 hi = pr[mi][ks][1] * xv[mi];
        PK8 u;
        u.v.a = __float22bfloat162_rn(make_float2(lo.x, lo.y));
        u.v.b = __float22bfloat162_rn(make_float2(lo.z, lo.w));
        u.v.c = __float22bfloat162_rn(make_float2(hi.x, hi.y));
        u.v.d = __float22bfloat162_rn(make_float2(hi.z, hi.w));
        af[mi] = u.f;
      }
#pragma unroll
      for (int ni = 0; ni < 4; ++ni) {
        bf16x8 bfr = *(const bf16x8*)&bsc[(ni * 16 + l15) * 72 + ks * 32 + quad * 8];
#pragma unroll
        for (int mi = 0; mi < 4; ++mi)
          acc[mi][ni] = __builtin_amdgcn_mfma_f32_16x16x32_bf16(
              af[mi], bfr, acc[mi][ni], 0, 0, 0);
      }
    }
  }
#undef BLOAD

  // ---- epilogue ----
#pragma unroll
  for (int mi = 0; mi < 4; ++mi) {
#pragma unroll
    for (int ni = 0; ni < 4; ++ni) {
      int row = row_m0 + wm + mi * 16 + quad * 4;
      int col = o0 + ni * 16 + l15;
      if (ATOMIC) {
        float* o = dst + (size_t)row * OUT_F + col;
        atomicAdd(o,             acc[mi][ni][0]);
        atomicAdd(o + OUT_F,     acc[mi][ni][1]);
        atomicAdd(o + 2 * OUT_F, acc[mi][ni][2]);
        atomicAdd(o + 3 * OUT_F, acc[mi][ni][3]);
      } else {
        float* o = dst + ((size_t)kc << 19) + (size_t)row * OUT_F + col;
        o[0]         = acc[mi][ni][0];
        o[OUT_F]     = acc[mi][ni][1];
        o[2 * OUT_F] = acc[mi][ni][2];
        o[3 * OUT_F] = acc[mi][ni][3];
      }
    }
  }
}

// ---------------------------------------------------------------------------
// Kernel 3: out[b][o] = sum_kc parts[kc][b][o] + sum_l p[b][l]*pb[o][l]
// (unchanged from R5; nparts==0 -> bias-only init for atomic fallback)
// ---------------------------------------------------------------------------
__global__ __launch_bounds__(256, 4) void k_reduce(
    const float* __restrict__ parts, const float* __restrict__ p_ws,
    const float* __restrict__ pb, float* __restrict__ out, int nparts)
{
  __shared__ float ps_l[2 * NLEAF];
  const int t  = threadIdx.x;
  const int b0 = blockIdx.x * 2;

  if (t < 32)
    ((f32x4*)ps_l)[t] = ((const f32x4*)(p_ws + (size_t)b0 * NLEAF))[t];
  __syncthreads();

  const int row = b0 + (t >> 7);
  const int c0  = (t & 127) * 4;
  const f32x4* ps = (const f32x4*)&ps_l[(t >> 7) * NLEAF];

  f32x4 a;
#pragma unroll
  for (int jo = 0; jo < 4; ++jo) {
    const f32x4* pbo = (const f32x4*)(pb + (size_t)(c0 + jo) * NLEAF);
    f32x4 s = (f32x4)(0.f);
#pragma unroll
    for (int lv = 0; lv < 16; ++lv) s += pbo[lv] * ps[lv];
    a[jo] = s.x + s.y + s.z + s.w;
  }

#pragma unroll 8
  for (int k = 0; k < nparts; ++k)
    a += *(const f32x4*)(parts + ((size_t)k << 19) + (size_t)row * OUT_F + c0);

  *(f32x4*)(out + (size_t)row * OUT_F + c0) = a;
}

// ---------------------------------------------------------------------------
extern "C" void kernel_launch(void* const* d_in, const int* in_sizes, int n_in,
                              void* d_out, int out_size, void* d_ws, size_t ws_size,
                              hipStream_t stream) {
  const float* xg = (const float*)d_in[0];   // x_gating [1024][512]
  const float* xl = (const float*)d_in[1];   // x_leaf   [1024][512]
  const float* gw = (const float*)d_in[2];   // [512][63]
  const float* gb = (const float*)d_in[3];   // [63]
  const float* pw = (const float*)d_in[4];   // [512][512][64]
  const float* pb = (const float*)d_in[5];   // [512][64]
  float* out = (float*)d_out;

  // ws: p fp32 (256 KB) | parts fp32 [SK][1024][512] (32 MB)
  const size_t P_BYTES = (size_t)B_SZ * NLEAF * 4;
  const size_t SLICE   = (size_t)B_SZ * OUT_F * 4;

  float* p_ws  = (float*)d_ws;
  float* parts = (float*)((char*)d_ws + P_BYTES);

  k_leafprobs<<<dim3(B_SZ), dim3(512), 0, stream>>>(xg, gw, gb, p_ws);

  if (ws_size >= P_BYTES + SK * SLICE) {
    k_fused<false><<<dim3(512), dim3(256), 0, stream>>>(xl, p_ws, pw, parts);
    k_reduce<<<dim3(512), dim3(256), 0, stream>>>(parts, p_ws, pb, out, SK);
  } else {
    k_reduce<<<dim3(512), dim3(256), 0, stream>>>(parts, p_ws, pb, out, 0);
    k_fused<true><<<dim3(512), dim3(256), 0, stream>>>(xl, p_ws, pw, out);
  }
}